// Round 1
// baseline (1408.751 us; speedup 1.0000x reference)
//
#include <hip/hip_runtime.h>
#include <hip/hip_bf16.h>

#define HH 512
#define FF 128
#define BB 2048
#define TT 96
#define NGATE 2048
#define NTOT 2176
#define GRP 16          // row groups (128 rows each)
#define CPB 32          // col-part blocks per group

typedef short short8 __attribute__((ext_vector_type(8)));
typedef float f32x4 __attribute__((ext_vector_type(4)));

union U128 { unsigned long long u[2]; short8 v; };

__device__ __forceinline__ float sigmoidf_(float x) { return 1.f / (1.f + __expf(-x)); }
__device__ __forceinline__ float tanhf_(float x) {
    float e = __expf(-2.f * fabsf(x));
    float t = (1.f - e) / (1.f + e);
    return x < 0.f ? -t : t;
}

// byte offset of element (m, k) in fragment order: 16(m) x 32(k) tiles of 1 KB,
// lane = (m&15) + 16*((k>>3)&3) holds bytes [lane*16, lane*16+16).
__device__ __forceinline__ size_t frag_off(int m, int k, int K) {
    return (size_t)((m >> 4) * (K >> 5) + (k >> 5)) * 1024
         + (size_t)(((k >> 3) & 3) * 256 + (m & 15) * 16 + (k & 7) * 2);
}

__device__ __forceinline__ short bf16bits(float f) {
    __hip_bfloat16 b = __float2bfloat16(f);
    return *(short*)&b;
}

// Gate col layout (n < 2048): octet o=n>>5, gate=(n>>3)&3, j=o*8+(n&7):
// each aligned 32-col group = [r(8) z(8) i_n(8) h_n(8)] for 8 consecutive j.
// Weights in B-fragment order. n>=2048: fc_w row -> Wfc.
__global__ __launch_bounds__(256) void build_weights(
    const float* __restrict__ w_ih, const float* __restrict__ w_hh,
    const float* __restrict__ b_ih, const float* __restrict__ b_hh,
    const float* __restrict__ fc_w, const float* __restrict__ fc_b,
    char* __restrict__ Wg, char* __restrict__ W0g, char* __restrict__ Wfc,
    float* __restrict__ bias, float* __restrict__ bias0)
{
    const int n = blockIdx.x;
    const int tid = threadIdx.x;
    __shared__ float wih_s[FF];
    const bool is_out = (n >= NGATE);
    int gate = 3, gidx = 0, f = 0;
    if (is_out) {
        f = n - NGATE;
    } else {
        int o = n >> 5;
        gate = (n >> 3) & 3;
        int j = o * 8 + (n & 7);
        gidx = (gate == 0) ? j : (gate == 1) ? (512 + j) : (1024 + j);
    }
    if (!is_out && gate != 3 && tid < FF) wih_s[tid] = w_ih[gidx * FF + tid];
    __syncthreads();

    for (int k = tid; k < HH; k += 256) {
        float w, w0;
        if (is_out) {
            w = fc_w[f * HH + k];
            w0 = 0.f;
        } else if (gate == 3) {
            w = w_hh[gidx * HH + k];
            w0 = w;
        } else {
            float comb = 0.f;
#pragma unroll 8
            for (int ff2 = 0; ff2 < FF; ++ff2) comb += wih_s[ff2] * fc_w[ff2 * HH + k];
            if (gate == 2) { w = comb; w0 = 0.f; }
            else { float whh = w_hh[gidx * HH + k]; w = whh + comb; w0 = whh; }
        }
        if (is_out) {
            *(short*)(Wfc + frag_off(f, k, HH)) = bf16bits(w);
        } else {
            *(short*)(Wg  + frag_off(n, k, HH)) = bf16bits(w);
            *(short*)(W0g + frag_off(n, k, HH)) = bf16bits(w0);
        }
    }
    if (tid == 0 && !is_out) {
        float b, b0;
        float cb = 0.f;
        if (gate != 3)
            for (int ff2 = 0; ff2 < FF; ++ff2) cb += fc_b[ff2] * w_ih[gidx * FF + ff2];
        if (gate <= 1)      { float s2 = b_ih[gidx] + b_hh[gidx]; b = s2 + cb; b0 = s2; }
        else if (gate == 2) { b = b_ih[gidx] + cb; b0 = b_ih[gidx]; }
        else                { b = b_hh[gidx]; b0 = b_hh[gidx]; }
        bias[n] = b; bias0[n] = b0;
    }
}

// hidden (fp32 row-major) -> h_0 bf16 in fragment order; zero sync counters.
__global__ __launch_bounds__(256) void init_misc(
    const float* __restrict__ hidden, char* __restrict__ hfrag, int* __restrict__ cnt)
{
    int i = blockIdx.x * 256 + threadIdx.x;  // 131072 granules of 8 k-elements
    int row = i >> 6, k0 = (i & 63) << 3;
    short8 v;
#pragma unroll
    for (int t = 0; t < 8; ++t) v[t] = bf16bits(hidden[(size_t)row * HH + k0 + t]);
    *(short8*)(hfrag + frag_off(row, k0, HH)) = v;
    if (i < GRP * 128) cnt[i] = 0;
}

#define GLD64(p) __hip_atomic_load((const unsigned long long*)(p), __ATOMIC_RELAXED, __HIP_MEMORY_SCOPE_AGENT)
#define GST64(p, v) __hip_atomic_store((unsigned long long*)(p), (v), __ATOMIC_RELAXED, __HIP_MEMORY_SCOPE_AGENT)

// Persistent GRU, group ping-pong edition.
// 256 blocks = 32 col-parts x 8 XCD slots; block (x, c) serves groups g0=x and
// g1=x+8 (both XCD-local; same c so one LDS weight stage feeds both).
// Per step, program order per block: [wait g0(s-1); compute g0(s); signal] then
// [wait g1(s-1); compute g1(s); signal]. By the time a block loops back to g0's
// wait, that barrier filled a full g1-phase (~2-3 us) earlier -> all barrier
// fill + skew + L2 round-trip latency hides behind the other group's compute,
// deterministically (no reliance on scheduler pairing).
// 1 block/CU, 4 waves (1/SIMD) -> deepened windows: A 8 K-chunks, Bt 4.
__global__ __launch_bounds__(256, 1) void gru_persist(
    const char* __restrict__ Wg, const char* __restrict__ W0g, const char* __restrict__ Wfc,
    const float* __restrict__ bias, const float* __restrict__ bias0,
    const float* __restrict__ fc_b, const float* __restrict__ hidden,
    char* __restrict__ hfrag0, char* __restrict__ hfrag1,
    float* __restrict__ out, int* __restrict__ cnt)
{
    __shared__ __align__(16) short Bs[32768];   // 64 KB: [ct(4)][chunk(16)][lane*8]
    __shared__ __align__(16) short hfr[2048];   // 4 KB packed h_new (reused per phase)

    const int tid = threadIdx.x;
    const int lane = tid & 63, w = tid >> 6;
    const int l15 = lane & 15, quad = lane >> 4;
    const int xcd = blockIdx.x & 7, c = blockIdx.x >> 3;
    const int g0 = xcd, g1 = xcd + 8;

    const char* bf  = Wfc + (size_t)(c & 7) * 16384 + lane * 16;
    const bool fcw = (w == (c >> 3));          // this wave also does the fc tile

    float bv[4];
#pragma unroll
    for (int ct = 0; ct < 4; ++ct) bv[ct] = bias[c * 64 + ct * 16 + l15];
    const float fcb = fc_b[(c & 7) * 16 + l15];

    // fp32 carry h per phase: [ph][rt][og][rg], j = c*16 + og*8 + l15 (l15<8)
    float carry[2][2][2][4];
    if (l15 < 8) {
#pragma unroll
        for (int ph = 0; ph < 2; ++ph)
#pragma unroll
            for (int rt = 0; rt < 2; ++rt)
#pragma unroll
                for (int og = 0; og < 2; ++og)
#pragma unroll
                    for (int rg = 0; rg < 4; ++rg)
                        carry[ph][rt][og][rg] =
                            hidden[(size_t)((xcd + 8 * ph) * 128 + w * 32 + rt * 16 + quad * 4 + rg) * HH
                                   + c * 16 + og * 8 + l15];
    }

    int* const cc0 = cnt + g0 * 128;
    int* const cc1 = cnt + g1 * 128;
    const size_t aoff0 = (size_t)(g0 * 8 + w * 2) * 16384 + (size_t)lane * 16;
    const size_t aoff1 = (size_t)(g1 * 8 + w * 2) * 16384 + (size_t)lane * 16;

    // ---- stage this block's 64 gate cols of Wg into LDS (once, shared by both groups) ----
    {
        const char* wsrc = Wg + (size_t)c * 65536;
#pragma unroll
        for (int i = 0; i < 16; ++i) {
            int idx = i * 256 + tid;
            *(int4*)((char*)Bs + idx * 16) = *(const int4*)(wsrc + (size_t)idx * 16);
        }
    }
    __syncthreads();

    // wait for a group's previous step (pre-satisfied in steady state)
    auto grp_wait = [&](int* ccp, int s) {
        if (tid == 0) {
            while (__hip_atomic_load(ccp + s, __ATOMIC_RELAXED, __HIP_MEMORY_SCOPE_AGENT) < CPB)
                __builtin_amdgcn_s_sleep(1);
        }
        __syncthreads();
        asm volatile("" ::: "memory");
    };

    // gates -> carry -> hfr pack -> frag store -> signal (NO spin here: the next
    // phase of this group only resumes after the other group's full phase)
    auto epilogue = [&](f32x4 (&acc)[2][4], float (&cr)[2][2][4], int s, int gg,
                        char* hout, int* ccp) {
#pragma unroll
        for (int rt = 0; rt < 2; ++rt)
#pragma unroll
            for (int og = 0; og < 2; ++og)
#pragma unroll
                for (int rg = 0; rg < 4; ++rg) {
                    float arz = acc[rt][2 * og][rg], anh = acc[rt][2 * og + 1][rg];
                    float zsh = __shfl_xor(arz, 8, 64);
                    float hsh = __shfl_xor(anh, 8, 64);
                    if (l15 < 8) {
                        float r = sigmoidf_(arz);
                        float z = sigmoidf_(zsh);
                        float nv = tanhf_(anh + r * hsh);
                        float hn = (1.f - z) * nv + z * cr[rt][og][rg];
                        cr[rt][og][rg] = hn;
                        hfr[(w * 32 + rt * 16 + quad * 4 + rg) * 16 + og * 8 + l15] = bf16bits(hn);
                    }
                }
        __syncthreads();
        {
            int lrow = tid >> 1, half = tid & 1;
            const unsigned long long* src = (const unsigned long long*)&hfr[lrow * 16 + half * 8];
            size_t off = (size_t)((gg * 8 + (lrow >> 4)) * 16 + (c >> 1)) * 1024
                       + (size_t)((((c << 1) + half) & 3) * 256 + (lrow & 15) * 16);
            GST64(hout + off, src[0]);
            GST64(hout + off + 8, src[1]);
        }
        asm volatile("s_waitcnt vmcnt(0)" ::: "memory");
        __syncthreads();
        if (tid == 0)
            __hip_atomic_fetch_add(ccp + s, 1, __ATOMIC_RELAXED, __HIP_MEMORY_SCOPE_AGENT);
    };

    // ---- step 0: x=0 weights streamed from global (one step per group, amortized) ----
    auto step0_phase = [&](float (&cr)[2][2][4], const char* ab0, int gg, int* ccp) {
        f32x4 acc[2][4];
#pragma unroll
        for (int ct = 0; ct < 4; ++ct) {
            float b0 = bias0[c * 64 + ct * 16 + l15];
            acc[0][ct] = (f32x4){b0, b0, b0, b0};
            acc[1][ct] = acc[0][ct];
        }
        const char* bb0 = W0g + (size_t)c * 65536 + lane * 16;
        U128 A[2][2]; short8 Bt[2][4];
#pragma unroll
        for (int p = 0; p < 2; ++p) {
#pragma unroll
            for (int rt = 0; rt < 2; ++rt) {
                A[p][rt].u[0] = GLD64(ab0 + rt * 16384 + p * 1024);
                A[p][rt].u[1] = GLD64(ab0 + rt * 16384 + p * 1024 + 8);
            }
#pragma unroll
            for (int ct = 0; ct < 4; ++ct)
                Bt[p][ct] = *(const short8*)(bb0 + ct * 16384 + p * 1024);
        }
#pragma unroll
        for (int it = 0; it < 16; ++it) {
            const int sl = it & 1;
#pragma unroll
            for (int rt = 0; rt < 2; ++rt)
#pragma unroll
                for (int ct = 0; ct < 4; ++ct)
                    acc[rt][ct] = __builtin_amdgcn_mfma_f32_16x16x32_bf16(A[sl][rt].v, Bt[sl][ct], acc[rt][ct], 0, 0, 0);
            if (it + 2 < 16) {
#pragma unroll
                for (int rt = 0; rt < 2; ++rt) {
                    A[sl][rt].u[0] = GLD64(ab0 + rt * 16384 + (it + 2) * 1024);
                    A[sl][rt].u[1] = GLD64(ab0 + rt * 16384 + (it + 2) * 1024 + 8);
                }
#pragma unroll
                for (int ct = 0; ct < 4; ++ct)
                    Bt[sl][ct] = *(const short8*)(bb0 + ct * 16384 + (it + 2) * 1024);
            }
        }
        epilogue(acc, cr, 0, gg, hfrag1, ccp);
    };

    // ---- steps 1..95 per group: B from LDS, A depth-8 window, fc fused ----
    auto step_phase = [&](float (&cr)[2][2][4], const char* ab, char* hout,
                          int gg, int* ccp, int s) {
        const int tt = 96 - s;
        f32x4 acc[2][4];
#pragma unroll
        for (int ct = 0; ct < 4; ++ct) {
            acc[0][ct] = (f32x4){bv[ct], bv[ct], bv[ct], bv[ct]};
            acc[1][ct] = acc[0][ct];
        }
        f32x4 fca[2] = {{0.f,0.f,0.f,0.f},{0.f,0.f,0.f,0.f}};

        // barrier-independent preloads first (weights LDS / fc weights)
        short8 Bt[4][4]; short8 Bf[4];
#pragma unroll
        for (int p = 0; p < 4; ++p)
#pragma unroll
            for (int ct = 0; ct < 4; ++ct)
                Bt[p][ct] = *(const short8*)((const char*)Bs + ct * 16384 + p * 1024 + lane * 16);
        if (fcw) {
#pragma unroll
            for (int p = 0; p < 4; ++p)
                Bf[p] = *(const short8*)(bf + p * 1024);
        }

        grp_wait(ccp, s - 1);

        U128 A[8][2];
#pragma unroll
        for (int p = 0; p < 8; ++p)
#pragma unroll
            for (int rt = 0; rt < 2; ++rt) {
                A[p][rt].u[0] = GLD64(ab + rt * 16384 + p * 1024);
                A[p][rt].u[1] = GLD64(ab + rt * 16384 + p * 1024 + 8);
            }

#pragma unroll
        for (int it = 0; it < 16; ++it) {
            const int sa = it & 7, sb = it & 3, sf = it & 3;
#pragma unroll
            for (int rt = 0; rt < 2; ++rt)
#pragma unroll
                for (int ct = 0; ct < 4; ++ct)
                    acc[rt][ct] = __builtin_amdgcn_mfma_f32_16x16x32_bf16(A[sa][rt].v, Bt[sb][ct], acc[rt][ct], 0, 0, 0);
            if (fcw) {
                fca[0] = __builtin_amdgcn_mfma_f32_16x16x32_bf16(A[sa][0].v, Bf[sf], fca[0], 0, 0, 0);
                fca[1] = __builtin_amdgcn_mfma_f32_16x16x32_bf16(A[sa][1].v, Bf[sf], fca[1], 0, 0, 0);
            }
            if (it + 8 < 16) {
#pragma unroll
                for (int rt = 0; rt < 2; ++rt) {
                    A[sa][rt].u[0] = GLD64(ab + rt * 16384 + (it + 8) * 1024);
                    A[sa][rt].u[1] = GLD64(ab + rt * 16384 + (it + 8) * 1024 + 8);
                }
            }
            if (it + 4 < 16) {
#pragma unroll
                for (int ct = 0; ct < 4; ++ct)
                    Bt[sb][ct] = *(const short8*)((const char*)Bs + ct * 16384 + (it + 4) * 1024 + lane * 16);
            }
            if (fcw && it + 4 < 16) Bf[sf] = *(const short8*)(bf + (it + 4) * 1024);
        }

        if (fcw) {
#pragma unroll
            for (int rt = 0; rt < 2; ++rt)
#pragma unroll
                for (int rg = 0; rg < 4; ++rg)
                    out[(size_t)(gg * 128 + w * 32 + rt * 16 + quad * 4 + rg) * (TT * FF)
                        + tt * FF + (c & 7) * 16 + l15] = fca[rt][rg] + fcb;
        }

        epilogue(acc, cr, s, gg, hout, ccp);
    };

    // ---- final projection: h_96 (hfrag0) -> out[:, 0, :] ----
    auto final_proj = [&](const char* ab0, int gg) {
        f32x4 fca[2] = {{0.f,0.f,0.f,0.f},{0.f,0.f,0.f,0.f}};
        U128 A[4][2]; short8 Bf[4];
#pragma unroll
        for (int p = 0; p < 4; ++p) {
#pragma unroll
            for (int rt = 0; rt < 2; ++rt) {
                A[p][rt].u[0] = GLD64(ab0 + rt * 16384 + p * 1024);
                A[p][rt].u[1] = GLD64(ab0 + rt * 16384 + p * 1024 + 8);
            }
            Bf[p] = *(const short8*)(bf + p * 1024);
        }
#pragma unroll
        for (int it = 0; it < 16; ++it) {
            const int sl = it & 3;
            fca[0] = __builtin_amdgcn_mfma_f32_16x16x32_bf16(A[sl][0].v, Bf[sl], fca[0], 0, 0, 0);
            fca[1] = __builtin_amdgcn_mfma_f32_16x16x32_bf16(A[sl][1].v, Bf[sl], fca[1], 0, 0, 0);
            if (it + 4 < 16) {
#pragma unroll
                for (int rt = 0; rt < 2; ++rt) {
                    A[sl][rt].u[0] = GLD64(ab0 + rt * 16384 + (it + 4) * 1024);
                    A[sl][rt].u[1] = GLD64(ab0 + rt * 16384 + (it + 4) * 1024 + 8);
                }
                Bf[sl] = *(const short8*)(bf + (it + 4) * 1024);
            }
        }
#pragma unroll
        for (int rt = 0; rt < 2; ++rt)
#pragma unroll
            for (int rg = 0; rg < 4; ++rg)
                out[(size_t)(gg * 128 + w * 32 + rt * 16 + quad * 4 + rg) * (TT * FF)
                    + (c & 7) * 16 + l15] = fca[rt][rg] + fcb;
    };

    // ---- main sequence: alternate the two groups' phases ----
    step0_phase(carry[0], hfrag0 + aoff0, g0, cc0);
    step0_phase(carry[1], hfrag0 + aoff1, g1, cc1);

    for (int s = 1; s < 96; ++s) {
        const char* abase = (s & 1) ? hfrag1 : hfrag0;
        char* ho = (s & 1) ? hfrag0 : hfrag1;
        step_phase(carry[0], abase + aoff0, ho, g0, cc0, s);
        step_phase(carry[1], abase + aoff1, ho, g1, cc1, s);
    }

    grp_wait(cc0, 95);
    if (fcw) final_proj(hfrag0 + aoff0, g0);
    grp_wait(cc1, 95);
    if (fcw) final_proj(hfrag0 + aoff1, g1);
}

extern "C" void kernel_launch(void* const* d_in, const int* in_sizes, int n_in,
                              void* d_out, int out_size, void* d_ws, size_t ws_size,
                              hipStream_t stream) {
    const float* hidden = (const float*)d_in[0];
    const float* w_ih   = (const float*)d_in[1];
    const float* w_hh   = (const float*)d_in[2];
    const float* b_ih   = (const float*)d_in[3];
    const float* b_hh   = (const float*)d_in[4];
    const float* fc_w   = (const float*)d_in[5];
    const float* fc_b   = (const float*)d_in[6];
    float* out = (float*)d_out;

    char* ws = (char*)d_ws;
    size_t off = 0;
    auto alloc = [&](size_t bytes) -> void* {
        void* p = ws + off;
        off += (bytes + 255) & ~(size_t)255;
        return p;
    };
    char* Wg   = (char*)alloc((size_t)NGATE * HH * 2);
    char* W0g  = (char*)alloc((size_t)NGATE * HH * 2);
    char* Wfc  = (char*)alloc((size_t)FF * HH * 2);
    float* bias  = (float*)alloc(NGATE * 4);
    float* bias0 = (float*)alloc(NGATE * 4);
    char* hfrag0 = (char*)alloc((size_t)BB * HH * 2);
    char* hfrag1 = (char*)alloc((size_t)BB * HH * 2);
    int* cnt = (int*)alloc(GRP * 128 * 4);

    build_weights<<<NTOT, 256, 0, stream>>>(w_ih, w_hh, b_ih, b_hh, fc_w, fc_b,
                                            Wg, W0g, Wfc, bias, bias0);
    init_misc<<<(BB * HH / 8 + 255) / 256, 256, 0, stream>>>(hidden, hfrag0, cnt);
    gru_persist<<<256, 256, 0, stream>>>(Wg, W0g, Wfc, bias, bias0, fc_b, hidden,
                                         hfrag0, hfrag1, out, cnt);
}

// Round 2
// 1240.149 us; speedup vs baseline: 1.1360x; 1.1360x over previous
//
#include <hip/hip_runtime.h>
#include <hip/hip_bf16.h>

#define HH 512
#define FF 128
#define BB 2048
#define TT 96
#define NSTEP 96
#define NGATE 2048
#define NTOT 2176
#define GRP 16          // row groups (128 rows each)
#define CPB 32          // col-part blocks per group

typedef short short8 __attribute__((ext_vector_type(8)));
typedef float f32x4 __attribute__((ext_vector_type(4)));

union U128 { unsigned long long u[2]; short8 v; };

__device__ __forceinline__ float sigmoidf_(float x) { return 1.f / (1.f + __expf(-x)); }
__device__ __forceinline__ float tanhf_(float x) {
    float e = __expf(-2.f * fabsf(x));
    float t = (1.f - e) / (1.f + e);
    return x < 0.f ? -t : t;
}

// byte offset of element (m, k) in fragment order: 16(m) x 32(k) tiles of 1 KB,
// lane = (m&15) + 16*((k>>3)&3) holds bytes [lane*16, lane*16+16).
__device__ __forceinline__ size_t frag_off(int m, int k, int K) {
    return (size_t)((m >> 4) * (K >> 5) + (k >> 5)) * 1024
         + (size_t)(((k >> 3) & 3) * 256 + (m & 15) * 16 + (k & 7) * 2);
}

__device__ __forceinline__ short bf16bits(float f) {
    __hip_bfloat16 b = __float2bfloat16(f);
    return *(short*)&b;
}

// Gate col layout (n < 2048): octet o=n>>5, gate=(n>>3)&3, j=o*8+(n&7):
// each aligned 32-col group = [r(8) z(8) i_n(8) h_n(8)] for 8 consecutive j.
// Weights in B-fragment order. n>=2048: fc_w row -> Wfc.
__global__ __launch_bounds__(256) void build_weights(
    const float* __restrict__ w_ih, const float* __restrict__ w_hh,
    const float* __restrict__ b_ih, const float* __restrict__ b_hh,
    const float* __restrict__ fc_w, const float* __restrict__ fc_b,
    char* __restrict__ Wg, char* __restrict__ W0g, char* __restrict__ Wfc,
    float* __restrict__ bias, float* __restrict__ bias0)
{
    const int n = blockIdx.x;
    const int tid = threadIdx.x;
    __shared__ float wih_s[FF];
    const bool is_out = (n >= NGATE);
    int gate = 3, gidx = 0, f = 0;
    if (is_out) {
        f = n - NGATE;
    } else {
        int o = n >> 5;
        gate = (n >> 3) & 3;
        int j = o * 8 + (n & 7);
        gidx = (gate == 0) ? j : (gate == 1) ? (512 + j) : (1024 + j);
    }
    if (!is_out && gate != 3 && tid < FF) wih_s[tid] = w_ih[gidx * FF + tid];
    __syncthreads();

    for (int k = tid; k < HH; k += 256) {
        float w, w0;
        if (is_out) {
            w = fc_w[f * HH + k];
            w0 = 0.f;
        } else if (gate == 3) {
            w = w_hh[gidx * HH + k];
            w0 = w;
        } else {
            float comb = 0.f;
#pragma unroll 8
            for (int ff2 = 0; ff2 < FF; ++ff2) comb += wih_s[ff2] * fc_w[ff2 * HH + k];
            if (gate == 2) { w = comb; w0 = 0.f; }
            else { float whh = w_hh[gidx * HH + k]; w = whh + comb; w0 = whh; }
        }
        if (is_out) {
            *(short*)(Wfc + frag_off(f, k, HH)) = bf16bits(w);
        } else {
            *(short*)(Wg  + frag_off(n, k, HH)) = bf16bits(w);
            *(short*)(W0g + frag_off(n, k, HH)) = bf16bits(w0);
        }
    }
    if (tid == 0 && !is_out) {
        float b, b0;
        float cb = 0.f;
        if (gate != 3)
            for (int ff2 = 0; ff2 < FF; ++ff2) cb += fc_b[ff2] * w_ih[gidx * FF + ff2];
        if (gate <= 1)      { float s2 = b_ih[gidx] + b_hh[gidx]; b = s2 + cb; b0 = s2; }
        else if (gate == 2) { b = b_ih[gidx] + cb; b0 = b_ih[gidx]; }
        else                { b = b_hh[gidx]; b0 = b_hh[gidx]; }
        bias[n] = b; bias0[n] = b0;
    }
}

// hidden (fp32 row-major) -> h_0 bf16 in fragment order; zero sync flags.
__global__ __launch_bounds__(256) void init_misc(
    const float* __restrict__ hidden, char* __restrict__ hfrag, int* __restrict__ cnt)
{
    int i = blockIdx.x * 256 + threadIdx.x;  // 131072 granules of 8 k-elements
    int row = i >> 6, k0 = (i & 63) << 3;
    short8 v;
#pragma unroll
    for (int t = 0; t < 8; ++t) v[t] = bf16bits(hidden[(size_t)row * HH + k0 + t]);
    *(short8*)(hfrag + frag_off(row, k0, HH)) = v;
    if (i < GRP * NSTEP * CPB) cnt[i] = 0;
}

#define GLD64(p) __hip_atomic_load((const unsigned long long*)(p), __ATOMIC_RELAXED, __HIP_MEMORY_SCOPE_AGENT)
#define GST64(p, v) __hip_atomic_store((unsigned long long*)(p), (v), __ATOMIC_RELAXED, __HIP_MEMORY_SCOPE_AGENT)

// Persistent GRU. 512 blocks = 16 row-groups(128 rows) x 32 col-parts(64 gate cols),
// 2 blocks/CU (LDS 68 KB, ~128 VGPR -> 2 waves/SIMD).
// Group map: g = (id&7) | ((((id>>3)^(id>>8))&1)<<3), c = (id>>3)&31.
//  - keeps XCD-locality (g%8 == id%8 under %8 dispatch)
//  - co-resident pair is a DIFFERENT group under both plausible pairings
//    (id,id+8) and (id,id+256): two independent recurrence chains per CU, so
//    one chain's barrier wait hides behind the other chain's compute.
// Barrier: per-block flag stores flag[g][s][c] (distinct addresses -> no 32-way
// same-address RMW serialization), lanes 0..31 of wave 0 poll the 32 flags.
// Same fence-free ordering as the r3-proven counter barrier (vmcnt(0) +
// __syncthreads before signal; relaxed agent-scope atomics throughout).
__global__ __launch_bounds__(256, 2) void gru_persist(
    const char* __restrict__ Wg, const char* __restrict__ W0g, const char* __restrict__ Wfc,
    const float* __restrict__ bias, const float* __restrict__ bias0,
    const float* __restrict__ fc_b, const float* __restrict__ hidden,
    char* __restrict__ hfrag0, char* __restrict__ hfrag1,
    float* __restrict__ out, int* __restrict__ cnt)
{
    __shared__ __align__(16) short Bs[32768];   // 64 KB: [ct(4)][chunk(16)][lane*8]
    __shared__ __align__(16) short hfr[2048];   // 4 KB packed h_new

    const int tid = threadIdx.x;
    const int lane = tid & 63, w = tid >> 6;
    const int l15 = lane & 15, quad = lane >> 4;
    const int idb = blockIdx.x;
    const int g = (idb & 7) | ((((idb >> 3) ^ (idb >> 8)) & 1) << 3);
    const int c = (idb >> 3) & 31;

    const char* aB0 = hfrag0 + (size_t)(g * 8 + w * 2) * 16384 + lane * 16;
    const char* aB1 = hfrag1 + (size_t)(g * 8 + w * 2) * 16384 + lane * 16;
    const char* bf  = Wfc + (size_t)(c & 7) * 16384 + lane * 16;
    const bool fcw = (w == (c >> 3));          // this wave also does the fc tile

    float bv[4];
#pragma unroll
    for (int ct = 0; ct < 4; ++ct) bv[ct] = bias[c * 64 + ct * 16 + l15];
    const float fcb = fc_b[(c & 7) * 16 + l15];

    // fp32 carry h for this wave's (row, j) ownership (j = c*16 + og*8 + l15, l15<8)
    float carry[2][2][4];
    if (l15 < 8) {
#pragma unroll
        for (int rt = 0; rt < 2; ++rt)
#pragma unroll
            for (int og = 0; og < 2; ++og)
#pragma unroll
                for (int rg = 0; rg < 4; ++rg)
                    carry[rt][og][rg] =
                        hidden[(size_t)(g * 128 + w * 32 + rt * 16 + quad * 4 + rg) * HH
                               + c * 16 + og * 8 + l15];
    }

    int* const fl = cnt + g * (NSTEP * CPB);   // flags for this group: [s][c]

    // ---- stage this block's 64 gate cols of Wg into LDS (once) ----
    {
        const char* wsrc = Wg + (size_t)c * 65536;
#pragma unroll
        for (int i = 0; i < 16; ++i) {
            int idx = i * 256 + tid;
            *(int4*)((char*)Bs + idx * 16) = *(const int4*)(wsrc + (size_t)idx * 16);
        }
    }
    __syncthreads();

    // wait for the group's step-s broadcast (32 flags, one per col-part)
    auto grp_wait = [&](int s) {
        if (w == 0 && lane < 32) {
            const int* fp = fl + s * CPB + lane;
            while (__hip_atomic_load(fp, __ATOMIC_RELAXED, __HIP_MEMORY_SCOPE_AGENT) == 0)
                __builtin_amdgcn_s_sleep(1);
        }
        __syncthreads();
        asm volatile("" ::: "memory");
    };

    // gates -> carry -> hfr pack -> frag store -> flag signal (no wait here)
    auto epilogue = [&](f32x4 (&acc)[2][4], int s, char* hout) {
#pragma unroll
        for (int rt = 0; rt < 2; ++rt)
#pragma unroll
            for (int og = 0; og < 2; ++og)
#pragma unroll
                for (int rg = 0; rg < 4; ++rg) {
                    float arz = acc[rt][2 * og][rg], anh = acc[rt][2 * og + 1][rg];
                    float zsh = __shfl_xor(arz, 8, 64);
                    float hsh = __shfl_xor(anh, 8, 64);
                    if (l15 < 8) {
                        float r = sigmoidf_(arz);
                        float z = sigmoidf_(zsh);
                        float nv = tanhf_(anh + r * hsh);
                        float hn = (1.f - z) * nv + z * carry[rt][og][rg];
                        carry[rt][og][rg] = hn;
                        hfr[(w * 32 + rt * 16 + quad * 4 + rg) * 16 + og * 8 + l15] = bf16bits(hn);
                    }
                }
        __syncthreads();
        {
            int lrow = tid >> 1, half = tid & 1;
            const unsigned long long* src = (const unsigned long long*)&hfr[lrow * 16 + half * 8];
            size_t off = (size_t)((g * 8 + (lrow >> 4)) * 16 + (c >> 1)) * 1024
                       + (size_t)((((c << 1) + half) & 3) * 256 + (lrow & 15) * 16);
            GST64(hout + off, src[0]);
            GST64(hout + off + 8, src[1]);
        }
        asm volatile("s_waitcnt vmcnt(0)" ::: "memory");
        __syncthreads();
        if (tid == 0)
            __hip_atomic_store(fl + s * CPB + c, 1, __ATOMIC_RELAXED, __HIP_MEMORY_SCOPE_AGENT);
    };

    // ---- step 0: x=0 weights streamed from global (one step, amortized) ----
    {
        f32x4 acc[2][4];
#pragma unroll
        for (int ct = 0; ct < 4; ++ct) {
            float b0 = bias0[c * 64 + ct * 16 + l15];
            acc[0][ct] = (f32x4){b0, b0, b0, b0};
            acc[1][ct] = acc[0][ct];
        }
        const char* bb0 = W0g + (size_t)c * 65536 + lane * 16;
        U128 A[2][2]; short8 Bt[2][4];
#pragma unroll
        for (int p = 0; p < 2; ++p) {
#pragma unroll
            for (int rt = 0; rt < 2; ++rt) {
                A[p][rt].u[0] = GLD64(aB0 + rt * 16384 + p * 1024);
                A[p][rt].u[1] = GLD64(aB0 + rt * 16384 + p * 1024 + 8);
            }
#pragma unroll
            for (int ct = 0; ct < 4; ++ct)
                Bt[p][ct] = *(const short8*)(bb0 + ct * 16384 + p * 1024);
        }
#pragma unroll
        for (int it = 0; it < 16; ++it) {
            const int sl = it & 1;
#pragma unroll
            for (int rt = 0; rt < 2; ++rt)
#pragma unroll
                for (int ct = 0; ct < 4; ++ct)
                    acc[rt][ct] = __builtin_amdgcn_mfma_f32_16x16x32_bf16(A[sl][rt].v, Bt[sl][ct], acc[rt][ct], 0, 0, 0);
            if (it + 2 < 16) {
#pragma unroll
                for (int rt = 0; rt < 2; ++rt) {
                    A[sl][rt].u[0] = GLD64(aB0 + rt * 16384 + (it + 2) * 1024);
                    A[sl][rt].u[1] = GLD64(aB0 + rt * 16384 + (it + 2) * 1024 + 8);
                }
#pragma unroll
                for (int ct = 0; ct < 4; ++ct)
                    Bt[sl][ct] = *(const short8*)(bb0 + ct * 16384 + (it + 2) * 1024);
            }
        }
        epilogue(acc, 0, hfrag1);
    }

    // ---- steps 1..95: B from LDS, A depth-6 window, fc fused ----
    for (int s = 1; s < 96; ++s) {
        const char* ab = (s & 1) ? aB1 : aB0;
        char* hout = (s & 1) ? hfrag0 : hfrag1;
        const int tt = 96 - s;

        // barrier-independent work first: acc init + weight preloads from LDS
        f32x4 acc[2][4];
#pragma unroll
        for (int ct = 0; ct < 4; ++ct) {
            acc[0][ct] = (f32x4){bv[ct], bv[ct], bv[ct], bv[ct]};
            acc[1][ct] = acc[0][ct];
        }
        f32x4 fca[2] = {{0.f,0.f,0.f,0.f},{0.f,0.f,0.f,0.f}};

        short8 Bt[2][4]; short8 Bf[4];
#pragma unroll
        for (int p = 0; p < 2; ++p)
#pragma unroll
            for (int ct = 0; ct < 4; ++ct)
                Bt[p][ct] = *(const short8*)((const char*)Bs + ct * 16384 + p * 1024 + lane * 16);
        if (fcw) {
#pragma unroll
            for (int p = 0; p < 4; ++p)
                Bf[p] = *(const short8*)(bf + p * 1024);
        }

        grp_wait(s - 1);

        U128 A[6][2];
#pragma unroll
        for (int p = 0; p < 6; ++p)
#pragma unroll
            for (int rt = 0; rt < 2; ++rt) {
                A[p][rt].u[0] = GLD64(ab + rt * 16384 + p * 1024);
                A[p][rt].u[1] = GLD64(ab + rt * 16384 + p * 1024 + 8);
            }

#pragma unroll
        for (int it = 0; it < 16; ++it) {
            const int sa = it % 6, sb = it & 1, sf = it & 3;
#pragma unroll
            for (int rt = 0; rt < 2; ++rt)
#pragma unroll
                for (int ct = 0; ct < 4; ++ct)
                    acc[rt][ct] = __builtin_amdgcn_mfma_f32_16x16x32_bf16(A[sa][rt].v, Bt[sb][ct], acc[rt][ct], 0, 0, 0);
            if (fcw) {
                fca[0] = __builtin_amdgcn_mfma_f32_16x16x32_bf16(A[sa][0].v, Bf[sf], fca[0], 0, 0, 0);
                fca[1] = __builtin_amdgcn_mfma_f32_16x16x32_bf16(A[sa][1].v, Bf[sf], fca[1], 0, 0, 0);
            }
            if (it + 6 < 16) {
#pragma unroll
                for (int rt = 0; rt < 2; ++rt) {
                    A[sa][rt].u[0] = GLD64(ab + rt * 16384 + (it + 6) * 1024);
                    A[sa][rt].u[1] = GLD64(ab + rt * 16384 + (it + 6) * 1024 + 8);
                }
            }
            if (it + 2 < 16) {
#pragma unroll
                for (int ct = 0; ct < 4; ++ct)
                    Bt[sb][ct] = *(const short8*)((const char*)Bs + ct * 16384 + (it + 2) * 1024 + lane * 16);
            }
            if (fcw && it + 4 < 16) Bf[sf] = *(const short8*)(bf + (it + 4) * 1024);
        }

        if (fcw) {
#pragma unroll
            for (int rt = 0; rt < 2; ++rt)
#pragma unroll
                for (int rg = 0; rg < 4; ++rg)
                    out[(size_t)(g * 128 + w * 32 + rt * 16 + quad * 4 + rg) * (TT * FF)
                        + tt * FF + (c & 7) * 16 + l15] = fca[rt][rg] + fcb;
        }

        epilogue(acc, s, hout);
    }

    // ---- final projection: h_96 (hfrag0) -> out[:, 0, :] ----
    grp_wait(95);
    if (fcw) {
        f32x4 fca[2] = {{0.f,0.f,0.f,0.f},{0.f,0.f,0.f,0.f}};
        U128 A[4][2]; short8 Bf[4];
#pragma unroll
        for (int p = 0; p < 4; ++p) {
#pragma unroll
            for (int rt = 0; rt < 2; ++rt) {
                A[p][rt].u[0] = GLD64(aB0 + rt * 16384 + p * 1024);
                A[p][rt].u[1] = GLD64(aB0 + rt * 16384 + p * 1024 + 8);
            }
            Bf[p] = *(const short8*)(bf + p * 1024);
        }
#pragma unroll
        for (int it = 0; it < 16; ++it) {
            const int sl = it & 3;
            fca[0] = __builtin_amdgcn_mfma_f32_16x16x32_bf16(A[sl][0].v, Bf[sl], fca[0], 0, 0, 0);
            fca[1] = __builtin_amdgcn_mfma_f32_16x16x32_bf16(A[sl][1].v, Bf[sl], fca[1], 0, 0, 0);
            if (it + 4 < 16) {
#pragma unroll
                for (int rt = 0; rt < 2; ++rt) {
                    A[sl][rt].u[0] = GLD64(aB0 + rt * 16384 + (it + 4) * 1024);
                    A[sl][rt].u[1] = GLD64(aB0 + rt * 16384 + (it + 4) * 1024 + 8);
                }
                Bf[sl] = *(const short8*)(bf + (it + 4) * 1024);
            }
        }
#pragma unroll
        for (int rt = 0; rt < 2; ++rt)
#pragma unroll
            for (int rg = 0; rg < 4; ++rg)
                out[(size_t)(g * 128 + w * 32 + rt * 16 + quad * 4 + rg) * (TT * FF)
                    + (c & 7) * 16 + l15] = fca[rt][rg] + fcb;
    }
}

extern "C" void kernel_launch(void* const* d_in, const int* in_sizes, int n_in,
                              void* d_out, int out_size, void* d_ws, size_t ws_size,
                              hipStream_t stream) {
    const float* hidden = (const float*)d_in[0];
    const float* w_ih   = (const float*)d_in[1];
    const float* w_hh   = (const float*)d_in[2];
    const float* b_ih   = (const float*)d_in[3];
    const float* b_hh   = (const float*)d_in[4];
    const float* fc_w   = (const float*)d_in[5];
    const float* fc_b   = (const float*)d_in[6];
    float* out = (float*)d_out;

    char* ws = (char*)d_ws;
    size_t off = 0;
    auto alloc = [&](size_t bytes) -> void* {
        void* p = ws + off;
        off += (bytes + 255) & ~(size_t)255;
        return p;
    };
    char* Wg   = (char*)alloc((size_t)NGATE * HH * 2);
    char* W0g  = (char*)alloc((size_t)NGATE * HH * 2);
    char* Wfc  = (char*)alloc((size_t)FF * HH * 2);
    float* bias  = (float*)alloc(NGATE * 4);
    float* bias0 = (float*)alloc(NGATE * 4);
    char* hfrag0 = (char*)alloc((size_t)BB * HH * 2);
    char* hfrag1 = (char*)alloc((size_t)BB * HH * 2);
    int* cnt = (int*)alloc((size_t)GRP * NSTEP * CPB * 4);

    build_weights<<<NTOT, 256, 0, stream>>>(w_ih, w_hh, b_ih, b_hh, fc_w, fc_b,
                                            Wg, W0g, Wfc, bias, bias0);
    init_misc<<<(BB * HH / 8 + 255) / 256, 256, 0, stream>>>(hidden, hfrag0, cnt);
    gru_persist<<<512, 256, 0, stream>>>(Wg, W0g, Wfc, bias, bias0, fc_b, hidden,
                                         hfrag0, hfrag1, out, cnt);
}

// Round 3
// 944.719 us; speedup vs baseline: 1.4912x; 1.3127x over previous
//
#include <hip/hip_runtime.h>
#include <hip/hip_bf16.h>

#define HH 512
#define FF 128
#define BB 2048
#define TT 96
#define NSTEP 96
#define NGATE 2048
#define NTOT 2176
#define GRP 16          // row groups (128 rows each) — XCD-local under id%8 dispatch
#define CPB 32          // col-part blocks per group

typedef short short8 __attribute__((ext_vector_type(8)));
typedef float f32x4 __attribute__((ext_vector_type(4)));

__device__ __forceinline__ float sigmoidf_(float x) { return 1.f / (1.f + __expf(-x)); }
__device__ __forceinline__ float tanhf_(float x) {
    float e = __expf(-2.f * fabsf(x));
    float t = (1.f - e) / (1.f + e);
    return x < 0.f ? -t : t;
}

// byte offset of element (m, k) in fragment order: 16(m) x 32(k) tiles of 1 KB,
// lane = (m&15) + 16*((k>>3)&3) holds bytes [lane*16, lane*16+16).
__device__ __forceinline__ size_t frag_off(int m, int k, int K) {
    return (size_t)((m >> 4) * (K >> 5) + (k >> 5)) * 1024
         + (size_t)(((k >> 3) & 3) * 256 + (m & 15) * 16 + (k & 7) * 2);
}

__device__ __forceinline__ short bf16bits(float f) {
    __hip_bfloat16 b = __float2bfloat16(f);
    return *(short*)&b;
}

// Gate col layout (n < 2048): octet o=n>>5, gate=(n>>3)&3, j=o*8+(n&7):
// each aligned 32-col group = [r(8) z(8) i_n(8) h_n(8)] for 8 consecutive j.
// Weights in B-fragment order. n>=2048: fc_w row -> Wfc.
__global__ __launch_bounds__(256) void build_weights(
    const float* __restrict__ w_ih, const float* __restrict__ w_hh,
    const float* __restrict__ b_ih, const float* __restrict__ b_hh,
    const float* __restrict__ fc_w, const float* __restrict__ fc_b,
    char* __restrict__ Wg, char* __restrict__ W0g, char* __restrict__ Wfc,
    float* __restrict__ bias, float* __restrict__ bias0)
{
    const int n = blockIdx.x;
    const int tid = threadIdx.x;
    __shared__ float wih_s[FF];
    const bool is_out = (n >= NGATE);
    int gate = 3, gidx = 0, f = 0;
    if (is_out) {
        f = n - NGATE;
    } else {
        int o = n >> 5;
        gate = (n >> 3) & 3;
        int j = o * 8 + (n & 7);
        gidx = (gate == 0) ? j : (gate == 1) ? (512 + j) : (1024 + j);
    }
    if (!is_out && gate != 3 && tid < FF) wih_s[tid] = w_ih[gidx * FF + tid];
    __syncthreads();

    for (int k = tid; k < HH; k += 256) {
        float w, w0;
        if (is_out) {
            w = fc_w[f * HH + k];
            w0 = 0.f;
        } else if (gate == 3) {
            w = w_hh[gidx * HH + k];
            w0 = w;
        } else {
            float comb = 0.f;
#pragma unroll 8
            for (int ff2 = 0; ff2 < FF; ++ff2) comb += wih_s[ff2] * fc_w[ff2 * HH + k];
            if (gate == 2) { w = comb; w0 = 0.f; }
            else { float whh = w_hh[gidx * HH + k]; w = whh + comb; w0 = whh; }
        }
        if (is_out) {
            *(short*)(Wfc + frag_off(f, k, HH)) = bf16bits(w);
        } else {
            *(short*)(Wg  + frag_off(n, k, HH)) = bf16bits(w);
            *(short*)(W0g + frag_off(n, k, HH)) = bf16bits(w0);
        }
    }
    if (tid == 0 && !is_out) {
        float b, b0;
        float cb = 0.f;
        if (gate != 3)
            for (int ff2 = 0; ff2 < FF; ++ff2) cb += fc_b[ff2] * w_ih[gidx * FF + ff2];
        if (gate <= 1)      { float s2 = b_ih[gidx] + b_hh[gidx]; b = s2 + cb; b0 = s2; }
        else if (gate == 2) { b = b_ih[gidx] + cb; b0 = b_ih[gidx]; }
        else                { b = b_hh[gidx]; b0 = b_hh[gidx]; }
        bias[n] = b; bias0[n] = b0;
    }
}

// hidden (fp32 row-major) -> h_0 bf16 in fragment order; zero sync flags.
__global__ __launch_bounds__(256) void init_misc(
    const float* __restrict__ hidden, char* __restrict__ hfrag, int* __restrict__ cnt)
{
    int i = blockIdx.x * 256 + threadIdx.x;  // 131072 granules of 8 k-elements
    int row = i >> 6, k0 = (i & 63) << 3;
    short8 v;
#pragma unroll
    for (int t = 0; t < 8; ++t) v[t] = bf16bits(hidden[(size_t)row * HH + k0 + t]);
    *(short8*)(hfrag + frag_off(row, k0, HH)) = v;
    if (i < GRP * NSTEP * CPB) cnt[i] = 0;
}

// Persistent GRU. 512 blocks = 16 row-groups(128 rows) x 32 col-parts(64 gate cols),
// 2 blocks/CU (LDS 68 KB, 128 VGPR -> 2 waves/SIMD). g = id&15 so co-resident
// blocks (id, id+256) serve the SAME group -> same A panel through the shared L1.
// h-exchange path: PLAIN cached 16-B loads/stores (not agent-scope atomics, which
// set sc0 and bypass L1 -> every A byte was an L2 transaction). Correctness vs
// stale L1: wave 0 executes buffer_inv sc0 (vector-L1 invalidate) after flag
// detect, before __syncthreads releases the A loads; h stores are write-through
// and drained by vmcnt(0) before the flag signal (proven ordering).
__global__ __launch_bounds__(256, 2) void gru_persist(
    const char* __restrict__ Wg, const char* __restrict__ W0g, const char* __restrict__ Wfc,
    const float* __restrict__ bias, const float* __restrict__ bias0,
    const float* __restrict__ fc_b, const float* __restrict__ hidden,
    char* __restrict__ hfrag0, char* __restrict__ hfrag1,
    float* __restrict__ out, int* __restrict__ cnt)
{
    __shared__ __align__(16) short Bs[32768];   // 64 KB: [ct(4)][chunk(16)][lane*8]
    __shared__ __align__(16) short hfr[2048];   // 4 KB packed h_new

    const int tid = threadIdx.x;
    const int lane = tid & 63, w = tid >> 6;
    const int l15 = lane & 15, quad = lane >> 4;
    const int g = blockIdx.x & 15, c = blockIdx.x >> 4;   // group on XCD (g&7)

    const char* aB0 = hfrag0 + (size_t)(g * 8 + w * 2) * 16384 + lane * 16;
    const char* aB1 = hfrag1 + (size_t)(g * 8 + w * 2) * 16384 + lane * 16;
    const char* bf  = Wfc + (size_t)(c & 7) * 16384 + lane * 16;
    const bool fcw = (w == (c >> 3));          // this wave also does the fc tile

    float bv[4];
#pragma unroll
    for (int ct = 0; ct < 4; ++ct) bv[ct] = bias[c * 64 + ct * 16 + l15];
    const float fcb = fc_b[(c & 7) * 16 + l15];

    // fp32 carry h for this wave's (row, j) ownership (j = c*16 + og*8 + l15, l15<8)
    float carry[2][2][4];
    if (l15 < 8) {
#pragma unroll
        for (int rt = 0; rt < 2; ++rt)
#pragma unroll
            for (int og = 0; og < 2; ++og)
#pragma unroll
                for (int rg = 0; rg < 4; ++rg)
                    carry[rt][og][rg] =
                        hidden[(size_t)(g * 128 + w * 32 + rt * 16 + quad * 4 + rg) * HH
                               + c * 16 + og * 8 + l15];
    }

    int* const fl = cnt + g * (NSTEP * CPB);   // flags for this group: [s][c]

    // ---- stage this block's 64 gate cols of Wg into LDS (once) ----
    {
        const char* wsrc = Wg + (size_t)c * 65536;
#pragma unroll
        for (int i = 0; i < 16; ++i) {
            int idx = i * 256 + tid;
            *(int4*)((char*)Bs + idx * 16) = *(const int4*)(wsrc + (size_t)idx * 16);
        }
    }
    __syncthreads();

    // wait for the group's step-s broadcast (32 flags, one per col-part), then
    // invalidate the vector L1 so this step's A loads can't see stale lines.
    auto grp_wait = [&](int s) {
        if (w == 0) {
            if (lane < 32) {
                const int* fp = fl + s * CPB + lane;
                while (__hip_atomic_load(fp, __ATOMIC_RELAXED, __HIP_MEMORY_SCOPE_AGENT) == 0)
                    __builtin_amdgcn_s_sleep(1);
            }
            asm volatile("buffer_inv sc0\n\ts_waitcnt vmcnt(0)" ::: "memory");
        }
        __syncthreads();
        asm volatile("" ::: "memory");
    };

    // gates -> carry -> hfr pack -> frag store -> flag signal (no wait here)
    auto epilogue = [&](f32x4 (&acc)[2][4], int s, char* hout) {
#pragma unroll
        for (int rt = 0; rt < 2; ++rt)
#pragma unroll
            for (int og = 0; og < 2; ++og)
#pragma unroll
                for (int rg = 0; rg < 4; ++rg) {
                    float arz = acc[rt][2 * og][rg], anh = acc[rt][2 * og + 1][rg];
                    float zsh = __shfl_xor(arz, 8, 64);
                    float hsh = __shfl_xor(anh, 8, 64);
                    if (l15 < 8) {
                        float r = sigmoidf_(arz);
                        float z = sigmoidf_(zsh);
                        float nv = tanhf_(anh + r * hsh);
                        float hn = (1.f - z) * nv + z * carry[rt][og][rg];
                        carry[rt][og][rg] = hn;
                        hfr[(w * 32 + rt * 16 + quad * 4 + rg) * 16 + og * 8 + l15] = bf16bits(hn);
                    }
                }
        __syncthreads();
        {
            int lrow = tid >> 1, half = tid & 1;
            size_t off = (size_t)((g * 8 + (lrow >> 4)) * 16 + (c >> 1)) * 1024
                       + (size_t)((((c << 1) + half) & 3) * 256 + (lrow & 15) * 16);
            *(int4*)(hout + off) = *(const int4*)&hfr[lrow * 16 + half * 8];
        }
        asm volatile("s_waitcnt vmcnt(0)" ::: "memory");
        __syncthreads();
        if (tid == 0)
            __hip_atomic_store(fl + s * CPB + c, 1, __ATOMIC_RELAXED, __HIP_MEMORY_SCOPE_AGENT);
    };

    // ---- step 0: x=0 weights streamed from global (one step, amortized) ----
    {
        f32x4 acc[2][4];
#pragma unroll
        for (int ct = 0; ct < 4; ++ct) {
            float b0 = bias0[c * 64 + ct * 16 + l15];
            acc[0][ct] = (f32x4){b0, b0, b0, b0};
            acc[1][ct] = acc[0][ct];
        }
        const char* bb0 = W0g + (size_t)c * 65536 + lane * 16;
        short8 A[2][2]; short8 Bt[2][4];
#pragma unroll
        for (int p = 0; p < 2; ++p) {
#pragma unroll
            for (int rt = 0; rt < 2; ++rt)
                A[p][rt] = *(const short8*)(aB0 + rt * 16384 + p * 1024);
#pragma unroll
            for (int ct = 0; ct < 4; ++ct)
                Bt[p][ct] = *(const short8*)(bb0 + ct * 16384 + p * 1024);
        }
#pragma unroll
        for (int it = 0; it < 16; ++it) {
            const int sl = it & 1;
#pragma unroll
            for (int rt = 0; rt < 2; ++rt)
#pragma unroll
                for (int ct = 0; ct < 4; ++ct)
                    acc[rt][ct] = __builtin_amdgcn_mfma_f32_16x16x32_bf16(A[sl][rt], Bt[sl][ct], acc[rt][ct], 0, 0, 0);
            if (it + 2 < 16) {
#pragma unroll
                for (int rt = 0; rt < 2; ++rt)
                    A[sl][rt] = *(const short8*)(aB0 + rt * 16384 + (it + 2) * 1024);
#pragma unroll
                for (int ct = 0; ct < 4; ++ct)
                    Bt[sl][ct] = *(const short8*)(bb0 + ct * 16384 + (it + 2) * 1024);
            }
        }
        epilogue(acc, 0, hfrag1);
    }

    // ---- steps 1..95: B from LDS, A depth-6 window, fc fused ----
    for (int s = 1; s < 96; ++s) {
        const char* ab = (s & 1) ? aB1 : aB0;
        char* hout = (s & 1) ? hfrag0 : hfrag1;
        const int tt = 96 - s;

        // barrier-independent work first: acc init + weight preloads from LDS
        f32x4 acc[2][4];
#pragma unroll
        for (int ct = 0; ct < 4; ++ct) {
            acc[0][ct] = (f32x4){bv[ct], bv[ct], bv[ct], bv[ct]};
            acc[1][ct] = acc[0][ct];
        }
        f32x4 fca[2] = {{0.f,0.f,0.f,0.f},{0.f,0.f,0.f,0.f}};

        short8 Bt[2][4]; short8 Bf[4];
#pragma unroll
        for (int p = 0; p < 2; ++p)
#pragma unroll
            for (int ct = 0; ct < 4; ++ct)
                Bt[p][ct] = *(const short8*)((const char*)Bs + ct * 16384 + p * 1024 + lane * 16);
        if (fcw) {
#pragma unroll
            for (int p = 0; p < 4; ++p)
                Bf[p] = *(const short8*)(bf + p * 1024);
        }

        grp_wait(s - 1);

        short8 A[6][2];
#pragma unroll
        for (int p = 0; p < 6; ++p)
#pragma unroll
            for (int rt = 0; rt < 2; ++rt)
                A[p][rt] = *(const short8*)(ab + rt * 16384 + p * 1024);

#pragma unroll
        for (int it = 0; it < 16; ++it) {
            const int sa = it % 6, sb = it & 1, sf = it & 3;
#pragma unroll
            for (int rt = 0; rt < 2; ++rt)
#pragma unroll
                for (int ct = 0; ct < 4; ++ct)
                    acc[rt][ct] = __builtin_amdgcn_mfma_f32_16x16x32_bf16(A[sa][rt], Bt[sb][ct], acc[rt][ct], 0, 0, 0);
            if (fcw) {
                fca[0] = __builtin_amdgcn_mfma_f32_16x16x32_bf16(A[sa][0], Bf[sf], fca[0], 0, 0, 0);
                fca[1] = __builtin_amdgcn_mfma_f32_16x16x32_bf16(A[sa][1], Bf[sf], fca[1], 0, 0, 0);
            }
            if (it + 6 < 16) {
#pragma unroll
                for (int rt = 0; rt < 2; ++rt)
                    A[sa][rt] = *(const short8*)(ab + rt * 16384 + (it + 6) * 1024);
            }
            if (it + 2 < 16) {
#pragma unroll
                for (int ct = 0; ct < 4; ++ct)
                    Bt[sb][ct] = *(const short8*)((const char*)Bs + ct * 16384 + (it + 2) * 1024 + lane * 16);
            }
            if (fcw && it + 4 < 16) Bf[sf] = *(const short8*)(bf + (it + 4) * 1024);
        }

        if (fcw) {
#pragma unroll
            for (int rt = 0; rt < 2; ++rt)
#pragma unroll
                for (int rg = 0; rg < 4; ++rg)
                    out[(size_t)(g * 128 + w * 32 + rt * 16 + quad * 4 + rg) * (TT * FF)
                        + tt * FF + (c & 7) * 16 + l15] = fca[rt][rg] + fcb;
        }

        epilogue(acc, s, hout);
    }

    // ---- final projection: h_96 (hfrag0) -> out[:, 0, :] ----
    grp_wait(95);
    if (fcw) {
        f32x4 fca[2] = {{0.f,0.f,0.f,0.f},{0.f,0.f,0.f,0.f}};
        short8 A[4][2]; short8 Bf[4];
#pragma unroll
        for (int p = 0; p < 4; ++p) {
#pragma unroll
            for (int rt = 0; rt < 2; ++rt)
                A[p][rt] = *(const short8*)(aB0 + rt * 16384 + p * 1024);
            Bf[p] = *(const short8*)(bf + p * 1024);
        }
#pragma unroll
        for (int it = 0; it < 16; ++it) {
            const int sl = it & 3;
            fca[0] = __builtin_amdgcn_mfma_f32_16x16x32_bf16(A[sl][0], Bf[sl], fca[0], 0, 0, 0);
            fca[1] = __builtin_amdgcn_mfma_f32_16x16x32_bf16(A[sl][1], Bf[sl], fca[1], 0, 0, 0);
            if (it + 4 < 16) {
#pragma unroll
                for (int rt = 0; rt < 2; ++rt)
                    A[sl][rt] = *(const short8*)(aB0 + rt * 16384 + (it + 4) * 1024);
                Bf[sl] = *(const short8*)(bf + (it + 4) * 1024);
            }
        }
#pragma unroll
        for (int rt = 0; rt < 2; ++rt)
#pragma unroll
            for (int rg = 0; rg < 4; ++rg)
                out[(size_t)(g * 128 + w * 32 + rt * 16 + quad * 4 + rg) * (TT * FF)
                    + (c & 7) * 16 + l15] = fca[rt][rg] + fcb;
    }
}

extern "C" void kernel_launch(void* const* d_in, const int* in_sizes, int n_in,
                              void* d_out, int out_size, void* d_ws, size_t ws_size,
                              hipStream_t stream) {
    const float* hidden = (const float*)d_in[0];
    const float* w_ih   = (const float*)d_in[1];
    const float* w_hh   = (const float*)d_in[2];
    const float* b_ih   = (const float*)d_in[3];
    const float* b_hh   = (const float*)d_in[4];
    const float* fc_w   = (const float*)d_in[5];
    const float* fc_b   = (const float*)d_in[6];
    float* out = (float*)d_out;

    char* ws = (char*)d_ws;
    size_t off = 0;
    auto alloc = [&](size_t bytes) -> void* {
        void* p = ws + off;
        off += (bytes + 255) & ~(size_t)255;
        return p;
    };
    char* Wg   = (char*)alloc((size_t)NGATE * HH * 2);
    char* W0g  = (char*)alloc((size_t)NGATE * HH * 2);
    char* Wfc  = (char*)alloc((size_t)FF * HH * 2);
    float* bias  = (float*)alloc(NGATE * 4);
    float* bias0 = (float*)alloc(NGATE * 4);
    char* hfrag0 = (char*)alloc((size_t)BB * HH * 2);
    char* hfrag1 = (char*)alloc((size_t)BB * HH * 2);
    int* cnt = (int*)alloc((size_t)GRP * NSTEP * CPB * 4);

    build_weights<<<NTOT, 256, 0, stream>>>(w_ih, w_hh, b_ih, b_hh, fc_w, fc_b,
                                            Wg, W0g, Wfc, bias, bias0);
    init_misc<<<(BB * HH / 8 + 255) / 256, 256, 0, stream>>>(hidden, hfrag0, cnt);
    gru_persist<<<512, 256, 0, stream>>>(Wg, W0g, Wfc, bias, bias0, fc_b, hidden,
                                         hfrag0, hfrag1, out, cnt);
}

// Round 4
// 918.596 us; speedup vs baseline: 1.5336x; 1.0284x over previous
//
#include <hip/hip_runtime.h>
#include <hip/hip_bf16.h>

#define HH 512
#define FF 128
#define BB 2048
#define TT 96
#define NSTEP 96
#define NGATE 2048
#define NTOT 2176
#define GRP 16          // row groups (128 rows each)
#define CPB 32          // col-part blocks per group

typedef short short8 __attribute__((ext_vector_type(8)));
typedef float f32x4 __attribute__((ext_vector_type(4)));

__device__ __forceinline__ float sigmoidf_(float x) { return 1.f / (1.f + __expf(-x)); }
__device__ __forceinline__ float tanhf_(float x) {
    float e = __expf(-2.f * fabsf(x));
    float t = (1.f - e) / (1.f + e);
    return x < 0.f ? -t : t;
}

// byte offset of element (m, k) in fragment order: 16(m) x 32(k) tiles of 1 KB,
// lane = (m&15) + 16*((k>>3)&3) holds bytes [lane*16, lane*16+16).
__device__ __forceinline__ size_t frag_off(int m, int k, int K) {
    return (size_t)((m >> 4) * (K >> 5) + (k >> 5)) * 1024
         + (size_t)(((k >> 3) & 3) * 256 + (m & 15) * 16 + (k & 7) * 2);
}

__device__ __forceinline__ short bf16bits(float f) {
    __hip_bfloat16 b = __float2bfloat16(f);
    return *(short*)&b;
}

// Gate col layout (n < 2048): octet o=n>>5, gate=(n>>3)&3, j=o*8+(n&7):
// each aligned 32-col group = [r(8) z(8) i_n(8) h_n(8)] for 8 consecutive j.
// Weights in B-fragment order. n>=2048: fc_w row -> Wfc.
__global__ __launch_bounds__(256) void build_weights(
    const float* __restrict__ w_ih, const float* __restrict__ w_hh,
    const float* __restrict__ b_ih, const float* __restrict__ b_hh,
    const float* __restrict__ fc_w, const float* __restrict__ fc_b,
    char* __restrict__ Wg, char* __restrict__ W0g, char* __restrict__ Wfc,
    float* __restrict__ bias, float* __restrict__ bias0)
{
    const int n = blockIdx.x;
    const int tid = threadIdx.x;
    __shared__ float wih_s[FF];
    const bool is_out = (n >= NGATE);
    int gate = 3, gidx = 0, f = 0;
    if (is_out) {
        f = n - NGATE;
    } else {
        int o = n >> 5;
        gate = (n >> 3) & 3;
        int j = o * 8 + (n & 7);
        gidx = (gate == 0) ? j : (gate == 1) ? (512 + j) : (1024 + j);
    }
    if (!is_out && gate != 3 && tid < FF) wih_s[tid] = w_ih[gidx * FF + tid];
    __syncthreads();

    for (int k = tid; k < HH; k += 256) {
        float w, w0;
        if (is_out) {
            w = fc_w[f * HH + k];
            w0 = 0.f;
        } else if (gate == 3) {
            w = w_hh[gidx * HH + k];
            w0 = w;
        } else {
            float comb = 0.f;
#pragma unroll 8
            for (int ff2 = 0; ff2 < FF; ++ff2) comb += wih_s[ff2] * fc_w[ff2 * HH + k];
            if (gate == 2) { w = comb; w0 = 0.f; }
            else { float whh = w_hh[gidx * HH + k]; w = whh + comb; w0 = whh; }
        }
        if (is_out) {
            *(short*)(Wfc + frag_off(f, k, HH)) = bf16bits(w);
        } else {
            *(short*)(Wg  + frag_off(n, k, HH)) = bf16bits(w);
            *(short*)(W0g + frag_off(n, k, HH)) = bf16bits(w0);
        }
    }
    if (tid == 0 && !is_out) {
        float b, b0;
        float cb = 0.f;
        if (gate != 3)
            for (int ff2 = 0; ff2 < FF; ++ff2) cb += fc_b[ff2] * w_ih[gidx * FF + ff2];
        if (gate <= 1)      { float s2 = b_ih[gidx] + b_hh[gidx]; b = s2 + cb; b0 = s2; }
        else if (gate == 2) { b = b_ih[gidx] + cb; b0 = b_ih[gidx]; }
        else                { b = b_hh[gidx]; b0 = b_hh[gidx]; }
        bias[n] = b; bias0[n] = b0;
    }
}

// hidden (fp32 row-major) -> h_0 bf16 in fragment order; zero sync flags.
__global__ __launch_bounds__(256) void init_misc(
    const float* __restrict__ hidden, char* __restrict__ hfrag, int* __restrict__ cnt)
{
    int i = blockIdx.x * 256 + threadIdx.x;  // 131072 granules of 8 k-elements
    int row = i >> 6, k0 = (i & 63) << 3;
    short8 v;
#pragma unroll
    for (int t = 0; t < 8; ++t) v[t] = bf16bits(hidden[(size_t)row * HH + k0 + t]);
    *(short8*)(hfrag + frag_off(row, k0, HH)) = v;
    if (i < GRP * NSTEP * CPB) cnt[i] = 0;
}

// Persistent GRU. 512 blocks = 16 row-groups(128 rows) x 32 col-parts(64 gate cols),
// 2 blocks/CU (LDS 68 KB, 128 VGPR -> 2 waves/SIMD).
// Group map: g = (id&7) | ((((id>>3)^(id>>8))&1)<<3), c = (id>>3)&31.
//  - keeps XCD-locality (g%8 == id%8 under %8 dispatch)
//  - co-resident pair is a DIFFERENT group under both plausible pairings
//    (id,id+8) and (id,id+256): two independent recurrence chains per CU, so
//    one chain's wait/epilogue/signal latency hides behind the other chain's
//    K-loop compute (this was neutral in r2 when the h-path was L2-atomic-bound;
//    now that loads are cached the phase overlap is the binding constraint).
// h-exchange: plain cached 16-B loads/stores; buffer_inv sc0 after flag detect
// kills stale L1 lines; vmcnt(0)+sync before flag signal orders the store.
__global__ __launch_bounds__(256, 2) void gru_persist(
    const char* __restrict__ Wg, const char* __restrict__ W0g, const char* __restrict__ Wfc,
    const float* __restrict__ bias, const float* __restrict__ bias0,
    const float* __restrict__ fc_b, const float* __restrict__ hidden,
    char* __restrict__ hfrag0, char* __restrict__ hfrag1,
    float* __restrict__ out, int* __restrict__ cnt)
{
    __shared__ __align__(16) short Bs[32768];   // 64 KB: [ct(4)][chunk(16)][lane*8]
    __shared__ __align__(16) short hfr[2048];   // 4 KB packed h_new

    const int tid = threadIdx.x;
    const int lane = tid & 63, w = tid >> 6;
    const int l15 = lane & 15, quad = lane >> 4;
    const int idb = blockIdx.x;
    const int g = (idb & 7) | ((((idb >> 3) ^ (idb >> 8)) & 1) << 3);
    const int c = (idb >> 3) & 31;

    const char* aB0 = hfrag0 + (size_t)(g * 8 + w * 2) * 16384 + lane * 16;
    const char* aB1 = hfrag1 + (size_t)(g * 8 + w * 2) * 16384 + lane * 16;
    const char* bf  = Wfc + (size_t)(c & 7) * 16384 + lane * 16;
    const bool fcw = (w == (c >> 3));          // this wave also does the fc tile

    float bv[4];
#pragma unroll
    for (int ct = 0; ct < 4; ++ct) bv[ct] = bias[c * 64 + ct * 16 + l15];
    const float fcb = fc_b[(c & 7) * 16 + l15];

    // fp32 carry h for this wave's (row, j) ownership (j = c*16 + og*8 + l15, l15<8)
    float carry[2][2][4];
    if (l15 < 8) {
#pragma unroll
        for (int rt = 0; rt < 2; ++rt)
#pragma unroll
            for (int og = 0; og < 2; ++og)
#pragma unroll
                for (int rg = 0; rg < 4; ++rg)
                    carry[rt][og][rg] =
                        hidden[(size_t)(g * 128 + w * 32 + rt * 16 + quad * 4 + rg) * HH
                               + c * 16 + og * 8 + l15];
    }

    int* const fl = cnt + g * (NSTEP * CPB);   // flags for this group: [s][c]

    // ---- stage this block's 64 gate cols of Wg into LDS (once) ----
    {
        const char* wsrc = Wg + (size_t)c * 65536;
#pragma unroll
        for (int i = 0; i < 16; ++i) {
            int idx = i * 256 + tid;
            *(int4*)((char*)Bs + idx * 16) = *(const int4*)(wsrc + (size_t)idx * 16);
        }
    }
    __syncthreads();

    // wait for the group's step-s broadcast (32 flags, one per col-part), then
    // invalidate the vector L1 so this step's A loads can't see stale lines.
    auto grp_wait = [&](int s) {
        if (w == 0) {
            if (lane < 32) {
                const int* fp = fl + s * CPB + lane;
                while (__hip_atomic_load(fp, __ATOMIC_RELAXED, __HIP_MEMORY_SCOPE_AGENT) == 0)
                    __builtin_amdgcn_s_sleep(1);
            }
            asm volatile("buffer_inv sc0\n\ts_waitcnt vmcnt(0)" ::: "memory");
        }
        __syncthreads();
        asm volatile("" ::: "memory");
    };

    // gates -> carry -> hfr pack -> frag store -> flag signal (no wait here).
    // Single full-wave sigmoid: lanes l15<8 hold r-preact, l15>=8 hold z-preact;
    // one shfl_xor(8) exchanges the activated values.
    auto epilogue = [&](f32x4 (&acc)[2][4], int s, char* hout) {
#pragma unroll
        for (int rt = 0; rt < 2; ++rt)
#pragma unroll
            for (int og = 0; og < 2; ++og)
#pragma unroll
                for (int rg = 0; rg < 4; ++rg) {
                    float arz = acc[rt][2 * og][rg], anh = acc[rt][2 * og + 1][rg];
                    float sg  = sigmoidf_(arz);          // all lanes: r (l15<8) / z (l15>=8)
                    float zv  = __shfl_xor(sg, 8, 64);   // lanes l15<8 receive z
                    float hsh = __shfl_xor(anh, 8, 64);  // lanes l15<8 receive h_n
                    if (l15 < 8) {
                        float nv = tanhf_(anh + sg * hsh);
                        float hn = (1.f - zv) * nv + zv * carry[rt][og][rg];
                        carry[rt][og][rg] = hn;
                        hfr[(w * 32 + rt * 16 + quad * 4 + rg) * 16 + og * 8 + l15] = bf16bits(hn);
                    }
                }
        __syncthreads();
        {
            int lrow = tid >> 1, half = tid & 1;
            size_t off = (size_t)((g * 8 + (lrow >> 4)) * 16 + (c >> 1)) * 1024
                       + (size_t)((((c << 1) + half) & 3) * 256 + (lrow & 15) * 16);
            *(int4*)(hout + off) = *(const int4*)&hfr[lrow * 16 + half * 8];
        }
        asm volatile("s_waitcnt vmcnt(0)" ::: "memory");
        __syncthreads();
        if (tid == 0)
            __hip_atomic_store(fl + s * CPB + c, 1, __ATOMIC_RELAXED, __HIP_MEMORY_SCOPE_AGENT);
    };

    // ---- step 0: x=0 weights streamed from global (one step, amortized) ----
    {
        f32x4 acc[2][4];
#pragma unroll
        for (int ct = 0; ct < 4; ++ct) {
            float b0 = bias0[c * 64 + ct * 16 + l15];
            acc[0][ct] = (f32x4){b0, b0, b0, b0};
            acc[1][ct] = acc[0][ct];
        }
        const char* bb0 = W0g + (size_t)c * 65536 + lane * 16;
        short8 A[2][2]; short8 Bt[2][4];
#pragma unroll
        for (int p = 0; p < 2; ++p) {
#pragma unroll
            for (int rt = 0; rt < 2; ++rt)
                A[p][rt] = *(const short8*)(aB0 + rt * 16384 + p * 1024);
#pragma unroll
            for (int ct = 0; ct < 4; ++ct)
                Bt[p][ct] = *(const short8*)(bb0 + ct * 16384 + p * 1024);
        }
#pragma unroll
        for (int it = 0; it < 16; ++it) {
            const int sl = it & 1;
#pragma unroll
            for (int rt = 0; rt < 2; ++rt)
#pragma unroll
                for (int ct = 0; ct < 4; ++ct)
                    acc[rt][ct] = __builtin_amdgcn_mfma_f32_16x16x32_bf16(A[sl][rt], Bt[sl][ct], acc[rt][ct], 0, 0, 0);
            if (it + 2 < 16) {
#pragma unroll
                for (int rt = 0; rt < 2; ++rt)
                    A[sl][rt] = *(const short8*)(aB0 + rt * 16384 + (it + 2) * 1024);
#pragma unroll
                for (int ct = 0; ct < 4; ++ct)
                    Bt[sl][ct] = *(const short8*)(bb0 + ct * 16384 + (it + 2) * 1024);
            }
        }
        epilogue(acc, 0, hfrag1);
    }

    // ---- steps 1..95: B from LDS, A depth-6 window, fc fused ----
    for (int s = 1; s < 96; ++s) {
        const char* ab = (s & 1) ? aB1 : aB0;
        char* hout = (s & 1) ? hfrag0 : hfrag1;
        const int tt = 96 - s;

        // barrier-independent work first: acc init + weight preloads from LDS
        f32x4 acc[2][4];
#pragma unroll
        for (int ct = 0; ct < 4; ++ct) {
            acc[0][ct] = (f32x4){bv[ct], bv[ct], bv[ct], bv[ct]};
            acc[1][ct] = acc[0][ct];
        }
        f32x4 fca[2] = {{0.f,0.f,0.f,0.f},{0.f,0.f,0.f,0.f}};

        short8 Bt[2][4]; short8 Bf[4];
#pragma unroll
        for (int p = 0; p < 2; ++p)
#pragma unroll
            for (int ct = 0; ct < 4; ++ct)
                Bt[p][ct] = *(const short8*)((const char*)Bs + ct * 16384 + p * 1024 + lane * 16);
        if (fcw) {
#pragma unroll
            for (int p = 0; p < 4; ++p)
                Bf[p] = *(const short8*)(bf + p * 1024);
        }

        grp_wait(s - 1);

        short8 A[6][2];
#pragma unroll
        for (int p = 0; p < 6; ++p)
#pragma unroll
            for (int rt = 0; rt < 2; ++rt)
                A[p][rt] = *(const short8*)(ab + rt * 16384 + p * 1024);

#pragma unroll
        for (int it = 0; it < 16; ++it) {
            const int sa = it % 6, sb = it & 1, sf = it & 3;
#pragma unroll
            for (int rt = 0; rt < 2; ++rt)
#pragma unroll
                for (int ct = 0; ct < 4; ++ct)
                    acc[rt][ct] = __builtin_amdgcn_mfma_f32_16x16x32_bf16(A[sa][rt], Bt[sb][ct], acc[rt][ct], 0, 0, 0);
            if (fcw) {
                fca[0] = __builtin_amdgcn_mfma_f32_16x16x32_bf16(A[sa][0], Bf[sf], fca[0], 0, 0, 0);
                fca[1] = __builtin_amdgcn_mfma_f32_16x16x32_bf16(A[sa][1], Bf[sf], fca[1], 0, 0, 0);
            }
            if (it + 6 < 16) {
#pragma unroll
                for (int rt = 0; rt < 2; ++rt)
                    A[sa][rt] = *(const short8*)(ab + rt * 16384 + (it + 6) * 1024);
            }
            if (it + 2 < 16) {
#pragma unroll
                for (int ct = 0; ct < 4; ++ct)
                    Bt[sb][ct] = *(const short8*)((const char*)Bs + ct * 16384 + (it + 2) * 1024 + lane * 16);
            }
            if (fcw && it + 4 < 16) Bf[sf] = *(const short8*)(bf + (it + 4) * 1024);
        }

        if (fcw) {
#pragma unroll
            for (int rt = 0; rt < 2; ++rt)
#pragma unroll
                for (int rg = 0; rg < 4; ++rg)
                    out[(size_t)(g * 128 + w * 32 + rt * 16 + quad * 4 + rg) * (TT * FF)
                        + tt * FF + (c & 7) * 16 + l15] = fca[rt][rg] + fcb;
        }

        epilogue(acc, s, hout);
    }

    // ---- final projection: h_96 (hfrag0) -> out[:, 0, :] ----
    grp_wait(95);
    if (fcw) {
        f32x4 fca[2] = {{0.f,0.f,0.f,0.f},{0.f,0.f,0.f,0.f}};
        short8 A[4][2]; short8 Bf[4];
#pragma unroll
        for (int p = 0; p < 4; ++p) {
#pragma unroll
            for (int rt = 0; rt < 2; ++rt)
                A[p][rt] = *(const short8*)(aB0 + rt * 16384 + p * 1024);
            Bf[p] = *(const short8*)(bf + p * 1024);
        }
#pragma unroll
        for (int it = 0; it < 16; ++it) {
            const int sl = it & 3;
            fca[0] = __builtin_amdgcn_mfma_f32_16x16x32_bf16(A[sl][0], Bf[sl], fca[0], 0, 0, 0);
            fca[1] = __builtin_amdgcn_mfma_f32_16x16x32_bf16(A[sl][1], Bf[sl], fca[1], 0, 0, 0);
            if (it + 4 < 16) {
#pragma unroll
                for (int rt = 0; rt < 2; ++rt)
                    A[sl][rt] = *(const short8*)(aB0 + rt * 16384 + (it + 4) * 1024);
                Bf[sl] = *(const short8*)(bf + (it + 4) * 1024);
            }
        }
#pragma unroll
        for (int rt = 0; rt < 2; ++rt)
#pragma unroll
            for (int rg = 0; rg < 4; ++rg)
                out[(size_t)(g * 128 + w * 32 + rt * 16 + quad * 4 + rg) * (TT * FF)
                    + (c & 7) * 16 + l15] = fca[rt][rg] + fcb;
    }
}

extern "C" void kernel_launch(void* const* d_in, const int* in_sizes, int n_in,
                              void* d_out, int out_size, void* d_ws, size_t ws_size,
                              hipStream_t stream) {
    const float* hidden = (const float*)d_in[0];
    const float* w_ih   = (const float*)d_in[1];
    const float* w_hh   = (const float*)d_in[2];
    const float* b_ih   = (const float*)d_in[3];
    const float* b_hh   = (const float*)d_in[4];
    const float* fc_w   = (const float*)d_in[5];
    const float* fc_b   = (const float*)d_in[6];
    float* out = (float*)d_out;

    char* ws = (char*)d_ws;
    size_t off = 0;
    auto alloc = [&](size_t bytes) -> void* {
        void* p = ws + off;
        off += (bytes + 255) & ~(size_t)255;
        return p;
    };
    char* Wg   = (char*)alloc((size_t)NGATE * HH * 2);
    char* W0g  = (char*)alloc((size_t)NGATE * HH * 2);
    char* Wfc  = (char*)alloc((size_t)FF * HH * 2);
    float* bias  = (float*)alloc(NGATE * 4);
    float* bias0 = (float*)alloc(NGATE * 4);
    char* hfrag0 = (char*)alloc((size_t)BB * HH * 2);
    char* hfrag1 = (char*)alloc((size_t)BB * HH * 2);
    int* cnt = (int*)alloc((size_t)GRP * NSTEP * CPB * 4);

    build_weights<<<NTOT, 256, 0, stream>>>(w_ih, w_hh, b_ih, b_hh, fc_w, fc_b,
                                            Wg, W0g, Wfc, bias, bias0);
    init_misc<<<(BB * HH / 8 + 255) / 256, 256, 0, stream>>>(hidden, hfrag0, cnt);
    gru_persist<<<512, 256, 0, stream>>>(Wg, W0g, Wfc, bias, bias0, fc_b, hidden,
                                         hfrag0, hfrag1, out, cnt);
}